// Round 1
// baseline (1246.436 us; speedup 1.0000x reference)
//
#include <hip/hip_runtime.h>
#include <stdint.h>

typedef unsigned long long u64;

__device__ __forceinline__ float sig_(float x) { return 1.0f / (1.0f + expf(-x)); }

// ---------------------------------------------------------------------------
// 3x3 stride-2 conv, SAME padding (pad_before=0, pad_after=1 for even inputs),
// fused leaky-relu(0.1). 8 output channels per thread; weights are wave-uniform
// (blockIdx.y picks the channel group) so they become scalar loads.
// ---------------------------------------------------------------------------
template <int CIN, int HIN, int WIN>
__global__ __launch_bounds__(256) void conv3x3s2_lrelu(
    const float* __restrict__ in, const float* __restrict__ wgt,
    const float* __restrict__ bias, float* __restrict__ out) {
  constexpr int HOUT = HIN / 2, WOUT = WIN / 2;
  constexpr int HWIN = HIN * WIN, HWOUT = HOUT * WOUT;
  const int b = blockIdx.z;
  const int oc0 = blockIdx.y * 8;
  const int COUT = gridDim.y * 8;
  const int sp = blockIdx.x * 256 + threadIdx.x;
  if (sp >= HWOUT) return;
  const int oy = sp / WOUT, ox = sp % WOUT;
  const int iy0 = oy * 2, ix0 = ox * 2;
  const float* inb = in + (size_t)b * CIN * HWIN + (size_t)iy0 * WIN + ix0;
  float acc[8];
#pragma unroll
  for (int u = 0; u < 8; u++) acc[u] = bias[oc0 + u];
  for (int ci = 0; ci < CIN; ++ci) {
    const float* ip = inb + (size_t)ci * HWIN;
    const float* wp = wgt + ((size_t)oc0 * CIN + ci) * 9;
#pragma unroll
    for (int ky = 0; ky < 3; ky++) {
      if (iy0 + ky < HIN) {
#pragma unroll
        for (int kx = 0; kx < 3; kx++) {
          if (ix0 + kx < WIN) {
            float v = ip[ky * WIN + kx];
#pragma unroll
            for (int u = 0; u < 8; u++)
              acc[u] = fmaf(v, wp[(size_t)u * CIN * 9 + ky * 3 + kx], acc[u]);
          }
        }
      }
    }
  }
  float* ob = out + ((size_t)b * COUT + oc0) * HWOUT + sp;
#pragma unroll
  for (int u = 0; u < 8; u++) {
    float r = acc[u];
    r = r > 0.0f ? r : 0.1f * r;
    ob[(size_t)u * HWOUT] = r;
  }
}

// ---------------------------------------------------------------------------
// 1x1 conv, no activation. COUT fixed = 255 (heads).
// ---------------------------------------------------------------------------
template <int CIN>
__global__ __launch_bounds__(256) void conv1x1_head(
    const float* __restrict__ in, const float* __restrict__ wgt,
    const float* __restrict__ bias, float* __restrict__ out, int HW) {
  const int sp = blockIdx.x * 256 + threadIdx.x;
  if (sp >= HW) return;
  const int oc = blockIdx.y;
  const int b = blockIdx.z;
  const float* ip = in + (size_t)b * CIN * HW + sp;
  const float* wp = wgt + (size_t)oc * CIN;
  float acc = bias[oc];
  for (int ci = 0; ci < CIN; ++ci) acc = fmaf(ip[(size_t)ci * HW], wp[ci], acc);
  out[((size_t)b * 255 + oc) * HW + sp] = acc;
}

// ---------------------------------------------------------------------------
// Decode both heads into per-candidate records:
//   cand[b][i][8] = { y1, x1, y2, x2, obj, class_conf, label, score }
// Candidate i<507: feat1 (13x13, anchors 81/135/344), else feat2 (26x26).
// score = obj*class_conf if >= 0.1 else 0 (matches reference threshold).
// Boxes already in the _correct_boxes frame: offset=0, scale=1, *416.
// ---------------------------------------------------------------------------
#define NCAND 2535
#define NKEEP 300

__global__ __launch_bounds__(256) void decode_kernel(
    const float* __restrict__ feat1, const float* __restrict__ feat2,
    float* __restrict__ cand) {
  const int gid = blockIdx.x * 256 + threadIdx.x;
  if (gid >= 8 * NCAND) return;
  const int b = gid / NCAND;
  const int i = gid % NCAND;
  const float* p;
  int rem, HW, W;
  float aw, ah;
  if (i < 507) {
    const int a = i / 169;
    rem = i % 169;
    HW = 169;
    W = 13;
    const float AW[3] = {81.f, 135.f, 344.f};
    const float AH[3] = {82.f, 169.f, 319.f};
    aw = AW[a];
    ah = AH[a];
    p = feat1 + ((size_t)b * 255 + a * 85) * 169 + rem;
  } else {
    const int j = i - 507;
    const int a = j / 676;
    rem = j % 676;
    HW = 676;
    W = 26;
    const float AW[3] = {10.f, 23.f, 37.f};
    const float AH[3] = {14.f, 27.f, 58.f};
    aw = AW[a];
    ah = AH[a];
    p = feat2 + ((size_t)b * 255 + a * 85) * 676 + rem;
  }
  const int gy = rem / W, gx = rem % W;
  const float invW = 1.0f / (float)W;
  float cx = (sig_(p[0]) + (float)gx) * invW;
  float cy = (sig_(p[(size_t)HW]) + (float)gy) * invW;  // H == W for both heads
  float bw = expf(p[(size_t)2 * HW]) * aw / 416.0f;
  float bh = expf(p[(size_t)3 * HW]) * ah / 416.0f;
  float obj = sig_(p[(size_t)4 * HW]);
  float best = p[(size_t)5 * HW];
  int lab = 0;
  for (int c = 1; c < 80; ++c) {
    float v = p[(size_t)(5 + c) * HW];
    if (v > best) {
      best = v;
      lab = c;
    }
  }
  float cc = sig_(best);
  float score = obj * cc;
  if (score < 0.1f) score = 0.0f;
  float* o = cand + (size_t)gid * 8;
  o[0] = (cy - bh * 0.5f) * 416.0f;
  o[1] = (cx - bw * 0.5f) * 416.0f;
  o[2] = (cy + bh * 0.5f) * 416.0f;
  o[3] = (cx + bw * 0.5f) * 416.0f;
  o[4] = obj;
  o[5] = cc;
  o[6] = (float)lab;
  o[7] = score;
}

// ---------------------------------------------------------------------------
// Per-batch top-300 (exact jax top_k ordering: score desc, tie -> lower index
// via packed key (score_bits<<32)|(0xFFFFFFFF-idx)) + greedy NMS via 300-bit
// suppression masks + sequential scan, then write [y1,x1,y2,x2,obj,cc,label].
// One block per batch image.
// ---------------------------------------------------------------------------
__global__ __launch_bounds__(256) void topk_nms_kernel(
    const float* __restrict__ cand, float* __restrict__ out) {
  const int b = blockIdx.x;
  const int tid = threadIdx.x;
  const float* cb = cand + (size_t)b * NCAND * 8;

  __shared__ u64 sel[NKEEP];
  __shared__ u64 red[4];
  __shared__ float bx[NKEEP][4];
  __shared__ float oc2[NKEEP][2];
  __shared__ int lb[NKEEP];
  __shared__ unsigned char validf[NKEEP];
  __shared__ u64 msk[NKEEP][5];
  __shared__ u64 keepw[5];

  // Each thread owns candidates tid + 256*k in registers as packed keys.
  u64 key[10];
#pragma unroll
  for (int k = 0; k < 10; k++) {
    const int idx = tid + k * 256;
    u64 kk = 0;
    if (idx < NCAND) {
      float s = cb[(size_t)idx * 8 + 7];
      if (s > 0.0f)
        kk = ((u64)__float_as_uint(s) << 32) | (u64)(0xFFFFFFFFu - (unsigned)idx);
    }
    key[k] = kk;
  }
  for (int t = tid; t < NKEEP; t += 256) sel[t] = 0;
  __syncthreads();

  // 300 iterations of block-wide argmax; winner removed from owner's registers.
  for (int i = 0; i < NKEEP; i++) {
    u64 m = key[0];
#pragma unroll
    for (int k = 1; k < 10; k++) m = key[k] > m ? key[k] : m;
#pragma unroll
    for (int off = 32; off >= 1; off >>= 1) {
      u64 o = __shfl_down(m, off);
      m = o > m ? o : m;
    }
    if ((tid & 63) == 0) red[tid >> 6] = m;
    __syncthreads();
    if (tid == 0) {
      u64 w = red[0];
      for (int j = 1; j < 4; j++) w = red[j] > w ? red[j] : w;
      sel[i] = w;
    }
    __syncthreads();
    const u64 win = sel[i];
    if (win == 0) break;  // uniform: no positive-score candidates left
#pragma unroll
    for (int k = 0; k < 10; k++)
      if (key[k] == win) key[k] = 0;
  }

  // Gather selected candidate data into LDS.
  for (int t = tid; t < NKEEP; t += 256) {
    const u64 w = sel[t];
    int idx = (int)(0xFFFFFFFFu - (unsigned)(w & 0xFFFFFFFFull));
    const bool v = (w != 0);
    if (!v) idx = 0;
    const float* c = cb + (size_t)idx * 8;
    bx[t][0] = c[0];
    bx[t][1] = c[1];
    bx[t][2] = c[2];
    bx[t][3] = c[3];
    oc2[t][0] = c[4];
    oc2[t][1] = c[5];
    lb[t] = (int)c[6];
    validf[t] = v ? 1 : 0;
  }
  __syncthreads();

  // Suppression bitmasks: msk[t] bit j set iff j<t, labels match, IoU>0.5.
  for (int t = tid; t < NKEEP; t += 256) {
    u64 w[5] = {0, 0, 0, 0, 0};
    if (validf[t]) {
      const float ay1 = bx[t][0], ax1 = bx[t][1], ay2 = bx[t][2], ax2 = bx[t][3];
      const float aarea = (ay2 - ay1) * (ax2 - ax1);
      const int al = lb[t];
      for (int j = 0; j < t; j++) {
        if (!validf[j] || lb[j] != al) continue;
        const float by1 = bx[j][0], bx1 = bx[j][1], by2 = bx[j][2], bx2 = bx[j][3];
        const float ty = fmaxf(ay1, by1), tx = fmaxf(ax1, bx1);
        const float ey = fminf(ay2, by2), ex = fminf(ax2, bx2);
        const float dy = fmaxf(ey - ty, 0.0f), dx = fmaxf(ex - tx, 0.0f);
        const float inter = dy * dx;
        const float barea = (by2 - by1) * (bx2 - bx1);
        const float iou = inter / (aarea + barea - inter + 1e-9f);
        if (iou > 0.5f) w[j >> 6] |= 1ull << (j & 63);
      }
    }
#pragma unroll
    for (int q = 0; q < 5; q++) msk[t][q] = w[q];
  }
  __syncthreads();

  // Sequential greedy scan (matches the fori_loop exactly).
  if (tid == 0) {
    u64 kw[5] = {0, 0, 0, 0, 0};
    for (int i = 0; i < NKEEP; i++) {
      if (!validf[i]) continue;
      u64 s = 0;
#pragma unroll
      for (int q = 0; q < 5; q++) s |= msk[i][q] & kw[q];
      if (s == 0) kw[i >> 6] |= 1ull << (i & 63);
    }
#pragma unroll
    for (int q = 0; q < 5; q++) keepw[q] = kw[q];
  }
  __syncthreads();

  float* ob = out + (size_t)b * NKEEP * 7;
  for (int t = tid; t < NKEEP; t += 256) {
    const bool k = (keepw[t >> 6] >> (t & 63)) & 1ull;
    float* r = ob + (size_t)t * 7;
    if (k) {
      r[0] = bx[t][0];
      r[1] = bx[t][1];
      r[2] = bx[t][2];
      r[3] = bx[t][3];
      r[4] = oc2[t][0];
      r[5] = oc2[t][1];
      r[6] = (float)lb[t];
    } else {
      r[0] = 0.0f; r[1] = 0.0f; r[2] = 0.0f; r[3] = 0.0f;
      r[4] = 0.0f; r[5] = 0.0f; r[6] = 0.0f;
    }
  }
}

// ---------------------------------------------------------------------------
// Workspace layout (floats). x3..cand alias the dead x1 region.
//   X1 : [0, 11075584)            8*32*208*208
//   X2 : [11075584, 16613376)     8*64*104*104
//   X3 : [0, 2768896)             8*128*52*52      (x1 dead)
//   X4 : [2768896, 4153344)       8*256*26*26
//   F2 : [4153344, 5532384)       8*255*26*26
//   X5 : [5532384, 6224608)       8*512*13*13
//   F1 : [6224608, 6569368)       8*255*13*13
//   CD : [6569368, 6731608)       8*2535*8
// Peak = 16613376 floats = 66.5 MB.
// ---------------------------------------------------------------------------
extern "C" void kernel_launch(void* const* d_in, const int* in_sizes, int n_in,
                              void* d_out, int out_size, void* d_ws,
                              size_t ws_size, hipStream_t stream) {
  const float* images = (const float*)d_in[0];
  const float* w1 = (const float*)d_in[1];
  const float* b1 = (const float*)d_in[2];
  const float* w2 = (const float*)d_in[3];
  const float* b2 = (const float*)d_in[4];
  const float* w3 = (const float*)d_in[5];
  const float* b3 = (const float*)d_in[6];
  const float* w4 = (const float*)d_in[7];
  const float* b4 = (const float*)d_in[8];
  const float* w5 = (const float*)d_in[9];
  const float* b5 = (const float*)d_in[10];
  const float* wh1 = (const float*)d_in[11];
  const float* bh1 = (const float*)d_in[12];
  const float* wh2 = (const float*)d_in[13];
  const float* bh2 = (const float*)d_in[14];
  float* ws = (float*)d_ws;

  float* x1 = ws + 0;
  float* x2 = ws + 11075584;
  float* x3 = ws + 0;
  float* x4 = ws + 2768896;
  float* f2 = ws + 4153344;
  float* x5 = ws + 5532384;
  float* f1 = ws + 6224608;
  float* cd = ws + 6569368;

  conv3x3s2_lrelu<3, 416, 416><<<dim3(169, 4, 8), 256, 0, stream>>>(images, w1, b1, x1);
  conv3x3s2_lrelu<32, 208, 208><<<dim3(43, 8, 8), 256, 0, stream>>>(x1, w2, b2, x2);
  conv3x3s2_lrelu<64, 104, 104><<<dim3(11, 16, 8), 256, 0, stream>>>(x2, w3, b3, x3);
  conv3x3s2_lrelu<128, 52, 52><<<dim3(3, 32, 8), 256, 0, stream>>>(x3, w4, b4, x4);
  conv1x1_head<256><<<dim3(3, 255, 8), 256, 0, stream>>>(x4, wh2, bh2, f2, 676);
  conv3x3s2_lrelu<256, 26, 26><<<dim3(1, 64, 8), 256, 0, stream>>>(x4, w5, b5, x5);
  conv1x1_head<512><<<dim3(1, 255, 8), 256, 0, stream>>>(x5, wh1, bh1, f1, 169);
  decode_kernel<<<80, 256, 0, stream>>>(f1, f2, cd);
  topk_nms_kernel<<<8, 256, 0, stream>>>(cd, (float*)d_out);
}

// Round 2
// 907.181 us; speedup vs baseline: 1.3740x; 1.3740x over previous
//
#include <hip/hip_runtime.h>
#include <stdint.h>

typedef unsigned long long u64;

__device__ __forceinline__ float sig_(float x) { return 1.0f / (1.0f + expf(-x)); }

#define NCAND 2535
#define NKEEP 300

// ---------------------------------------------------------------------------
// 3x3 stride-2 conv, SAME padding (pad_before=0, pad_after=1), fused
// leaky-relu(0.1). OCT output channels per thread; weights are wave-uniform
// (blockIdx.y picks the channel group) -> scalar s_load. Edge masking only at
// ky==2 (last out row) / kx==2 (last out col).
// ---------------------------------------------------------------------------
template <int CIN, int HIN, int WIN, int OCT>
__global__ __launch_bounds__(256) void conv3x3s2_lrelu(
    const float* __restrict__ in, const float* __restrict__ wgt,
    const float* __restrict__ bias, float* __restrict__ out) {
  constexpr int HOUT = HIN / 2, WOUT = WIN / 2;
  constexpr int HWIN = HIN * WIN, HWOUT = HOUT * WOUT;
  const int b = blockIdx.z;
  const int oc0 = blockIdx.y * OCT;
  const int COUT = gridDim.y * OCT;
  const int sp = blockIdx.x * 256 + threadIdx.x;
  if (sp >= HWOUT) return;
  const int oy = sp / WOUT, ox = sp % WOUT;
  const int iy0 = oy * 2, ix0 = ox * 2;
  const bool okY = (iy0 + 2 < HIN);  // false only on the last output row
  const bool okX = (ix0 + 2 < WIN);  // false only on the last output col
  const float* inb = in + (size_t)b * CIN * HWIN + (size_t)iy0 * WIN + ix0;
  float acc[OCT];
#pragma unroll
  for (int u = 0; u < OCT; u++) acc[u] = bias[oc0 + u];
  for (int ci = 0; ci < CIN; ++ci) {
    const float* ip = inb + (size_t)ci * HWIN;
    float v[9];
#pragma unroll
    for (int ky = 0; ky < 3; ky++) {
#pragma unroll
      for (int kx = 0; kx < 3; kx++) {
        const bool ok = (ky < 2 || okY) && (kx < 2 || okX);
        v[ky * 3 + kx] = ok ? ip[ky * WIN + kx] : 0.0f;
      }
    }
    const float* wp = wgt + ((size_t)oc0 * CIN + ci) * 9;
#pragma unroll
    for (int u = 0; u < OCT; u++) {
#pragma unroll
      for (int k = 0; k < 9; k++)
        acc[u] = fmaf(v[k], wp[(size_t)u * CIN * 9 + k], acc[u]);
    }
  }
  float* ob = out + ((size_t)b * COUT + oc0) * HWOUT + sp;
#pragma unroll
  for (int u = 0; u < OCT; u++) {
    float r = acc[u];
    r = r > 0.0f ? r : 0.1f * r;
    ob[(size_t)u * HWOUT] = r;
  }
}

// ---------------------------------------------------------------------------
// 1x1 conv head (COUT=255 total), OCT channels per thread, no activation.
// ---------------------------------------------------------------------------
template <int CIN, int OCT>
__global__ __launch_bounds__(256) void conv1x1_head(
    const float* __restrict__ in, const float* __restrict__ wgt,
    const float* __restrict__ bias, float* __restrict__ out, int HW) {
  const int sp = blockIdx.x * 256 + threadIdx.x;
  if (sp >= HW) return;
  const int oc0 = blockIdx.y * OCT;
  const int b = blockIdx.z;
  const float* ip = in + (size_t)b * CIN * HW + sp;
  float acc[OCT];
#pragma unroll
  for (int u = 0; u < OCT; u++) acc[u] = bias[oc0 + u];
  for (int ci = 0; ci < CIN; ++ci) {
    const float v = ip[(size_t)ci * HW];
#pragma unroll
    for (int u = 0; u < OCT; u++)
      acc[u] = fmaf(v, wgt[(size_t)(oc0 + u) * CIN + ci], acc[u]);
  }
#pragma unroll
  for (int u = 0; u < OCT; u++)
    out[((size_t)b * 255 + oc0 + u) * HW + sp] = acc[u];
}

// ---------------------------------------------------------------------------
// Decode both heads into per-candidate records AND packed sort keys.
//   cand[b][i][8] = { y1, x1, y2, x2, obj, class_conf, label, score }
//   key[b][i] = (float_bits(score) << 32) | (0xFFFFFFFF - i)
// All keys distinct; key order == jax.lax.top_k order (desc score, ties ->
// lower index first).
// ---------------------------------------------------------------------------
__global__ __launch_bounds__(256) void decode_kernel(
    const float* __restrict__ feat1, const float* __restrict__ feat2,
    float* __restrict__ cand, u64* __restrict__ keys) {
  const int gid = blockIdx.x * 256 + threadIdx.x;
  if (gid >= 8 * NCAND) return;
  const int b = gid / NCAND;
  const int i = gid % NCAND;
  const float* p;
  int rem, HW, W;
  float aw, ah;
  if (i < 507) {
    const int a = i / 169;
    rem = i % 169;
    HW = 169;
    W = 13;
    const float AW[3] = {81.f, 135.f, 344.f};
    const float AH[3] = {82.f, 169.f, 319.f};
    aw = AW[a];
    ah = AH[a];
    p = feat1 + ((size_t)b * 255 + a * 85) * 169 + rem;
  } else {
    const int j = i - 507;
    const int a = j / 676;
    rem = j % 676;
    HW = 676;
    W = 26;
    const float AW[3] = {10.f, 23.f, 37.f};
    const float AH[3] = {14.f, 27.f, 58.f};
    aw = AW[a];
    ah = AH[a];
    p = feat2 + ((size_t)b * 255 + a * 85) * 676 + rem;
  }
  const int gy = rem / W, gx = rem % W;
  const float invW = 1.0f / (float)W;
  float cx = (sig_(p[0]) + (float)gx) * invW;
  float cy = (sig_(p[(size_t)HW]) + (float)gy) * invW;  // H == W for both heads
  float bw = expf(p[(size_t)2 * HW]) * aw / 416.0f;
  float bh = expf(p[(size_t)3 * HW]) * ah / 416.0f;
  float obj = sig_(p[(size_t)4 * HW]);
  float best = p[(size_t)5 * HW];
  int lab = 0;
  for (int c = 1; c < 80; ++c) {
    float v = p[(size_t)(5 + c) * HW];
    if (v > best) {
      best = v;
      lab = c;
    }
  }
  float cc = sig_(best);
  float score = obj * cc;
  if (score < 0.1f) score = 0.0f;
  float* o = cand + (size_t)gid * 8;
  o[0] = (cy - bh * 0.5f) * 416.0f;
  o[1] = (cx - bw * 0.5f) * 416.0f;
  o[2] = (cy + bh * 0.5f) * 416.0f;
  o[3] = (cx + bw * 0.5f) * 416.0f;
  o[4] = obj;
  o[5] = cc;
  o[6] = (float)lab;
  o[7] = score;
  keys[gid] = ((u64)__float_as_uint(score) << 32) |
              (u64)(0xFFFFFFFFu - (unsigned)i);
}

// ---------------------------------------------------------------------------
// Exact top-300 via rank: rank(i) = #{j : key_j > key_i}. Keys distinct ->
// rank is a bijection; sel[rank] = i for rank < 300 reproduces top_k exactly.
// grid (10, 8): blockIdx.y = image, 256 candidates per block.
// ---------------------------------------------------------------------------
__global__ __launch_bounds__(256) void rank_select_kernel(
    const u64* __restrict__ keys, int* __restrict__ sel) {
  const int b = blockIdx.y;
  __shared__ u64 k[NCAND];
  const u64* kb = keys + (size_t)b * NCAND;
  for (int t = threadIdx.x; t < NCAND; t += 256) k[t] = kb[t];
  __syncthreads();
  const int idx = blockIdx.x * 256 + threadIdx.x;
  if (idx >= NCAND) return;
  const u64 me = k[idx];
  int rank = 0;
#pragma unroll 4
  for (int j = 0; j < NCAND; j++) rank += (k[j] > me) ? 1 : 0;
  if (rank < NKEEP) sel[b * NKEEP + rank] = idx;
}

// ---------------------------------------------------------------------------
// Per-image NMS on the 300 selected candidates: 300x300 suppression bitmask
// (parallel) + sequential greedy scan (matches fori_loop exactly) + output
// write [y1,x1,y2,x2,obj,cc,label] or zeros.
// ---------------------------------------------------------------------------
__global__ __launch_bounds__(256) void nms_kernel(
    const float* __restrict__ cand, const int* __restrict__ sel,
    float* __restrict__ out) {
  const int b = blockIdx.x;
  const int tid = threadIdx.x;
  const float* cb = cand + (size_t)b * NCAND * 8;

  __shared__ float bx[NKEEP][4];
  __shared__ float oc2[NKEEP][2];
  __shared__ int lb[NKEEP];
  __shared__ unsigned char validf[NKEEP];
  __shared__ u64 msk[NKEEP][5];
  __shared__ u64 keepw[5];

  for (int t = tid; t < NKEEP; t += 256) {
    const int idx = sel[b * NKEEP + t];
    const float* c = cb + (size_t)idx * 8;
    bx[t][0] = c[0];
    bx[t][1] = c[1];
    bx[t][2] = c[2];
    bx[t][3] = c[3];
    oc2[t][0] = c[4];
    oc2[t][1] = c[5];
    lb[t] = (int)c[6];
    validf[t] = (c[7] > 0.0f) ? 1 : 0;
  }
  __syncthreads();

  // msk[t] bit j set iff j < t, same label, both valid, IoU > 0.5.
  for (int t = tid; t < NKEEP; t += 256) {
    u64 w[5] = {0, 0, 0, 0, 0};
    if (validf[t]) {
      const float ay1 = bx[t][0], ax1 = bx[t][1], ay2 = bx[t][2], ax2 = bx[t][3];
      const float aarea = (ay2 - ay1) * (ax2 - ax1);
      const int al = lb[t];
      for (int j = 0; j < t; j++) {
        if (!validf[j] || lb[j] != al) continue;
        const float by1 = bx[j][0], bx1 = bx[j][1], by2 = bx[j][2], bx2 = bx[j][3];
        const float ty = fmaxf(ay1, by1), tx = fmaxf(ax1, bx1);
        const float ey = fminf(ay2, by2), ex = fminf(ax2, bx2);
        const float dy = fmaxf(ey - ty, 0.0f), dx = fmaxf(ex - tx, 0.0f);
        const float inter = dy * dx;
        const float barea = (by2 - by1) * (bx2 - bx1);
        const float iou = inter / (aarea + barea - inter + 1e-9f);
        if (iou > 0.5f) w[j >> 6] |= 1ull << (j & 63);
      }
    }
#pragma unroll
    for (int q = 0; q < 5; q++) msk[t][q] = w[q];
  }
  __syncthreads();

  if (tid == 0) {
    u64 kw[5] = {0, 0, 0, 0, 0};
    for (int i = 0; i < NKEEP; i++) {
      if (!validf[i]) continue;
      u64 s = 0;
#pragma unroll
      for (int q = 0; q < 5; q++) s |= msk[i][q] & kw[q];
      if (s == 0) kw[i >> 6] |= 1ull << (i & 63);
    }
#pragma unroll
    for (int q = 0; q < 5; q++) keepw[q] = kw[q];
  }
  __syncthreads();

  float* ob = out + (size_t)b * NKEEP * 7;
  for (int t = tid; t < NKEEP; t += 256) {
    const bool k = (keepw[t >> 6] >> (t & 63)) & 1ull;
    float* r = ob + (size_t)t * 7;
    if (k) {
      r[0] = bx[t][0];
      r[1] = bx[t][1];
      r[2] = bx[t][2];
      r[3] = bx[t][3];
      r[4] = oc2[t][0];
      r[5] = oc2[t][1];
      r[6] = (float)lb[t];
    } else {
      r[0] = 0.0f; r[1] = 0.0f; r[2] = 0.0f; r[3] = 0.0f;
      r[4] = 0.0f; r[5] = 0.0f; r[6] = 0.0f;
    }
  }
}

// ---------------------------------------------------------------------------
// Workspace layout (float offsets):
//   X1  : [0, 11075584)          8*32*208*208
//   X2  : [11075584, 16613376)   8*64*104*104
//   X3  : [0, 2768896)           (x1 dead)
//   X4  : [2768896, 4153344)
//   F2  : [4153344, 5532384)
//   X5  : [5532384, 6224608)
//   F1  : [6224608, 6569368)
//   CD  : [6569368, 6731608)     8*2535*8
//   KEY : [6731608, 6772168)     8*2535 u64 (byte-offset 8-aligned)
//   SEL : [6772168, 6774568)     8*300 int
// Peak = 16613376 floats = 66.5 MB (unchanged).
// ---------------------------------------------------------------------------
extern "C" void kernel_launch(void* const* d_in, const int* in_sizes, int n_in,
                              void* d_out, int out_size, void* d_ws,
                              size_t ws_size, hipStream_t stream) {
  const float* images = (const float*)d_in[0];
  const float* w1 = (const float*)d_in[1];
  const float* b1 = (const float*)d_in[2];
  const float* w2 = (const float*)d_in[3];
  const float* b2 = (const float*)d_in[4];
  const float* w3 = (const float*)d_in[5];
  const float* b3 = (const float*)d_in[6];
  const float* w4 = (const float*)d_in[7];
  const float* b4 = (const float*)d_in[8];
  const float* w5 = (const float*)d_in[9];
  const float* b5 = (const float*)d_in[10];
  const float* wh1 = (const float*)d_in[11];
  const float* bh1 = (const float*)d_in[12];
  const float* wh2 = (const float*)d_in[13];
  const float* bh2 = (const float*)d_in[14];
  float* ws = (float*)d_ws;

  float* x1 = ws + 0;
  float* x2 = ws + 11075584;
  float* x3 = ws + 0;
  float* x4 = ws + 2768896;
  float* f2 = ws + 4153344;
  float* x5 = ws + 5532384;
  float* f1 = ws + 6224608;
  float* cd = ws + 6569368;
  u64* keys = (u64*)(ws + 6731608);
  int* sel = (int*)(ws + 6772168);

  conv3x3s2_lrelu<3, 416, 416, 16><<<dim3(169, 2, 8), 256, 0, stream>>>(images, w1, b1, x1);
  conv3x3s2_lrelu<32, 208, 208, 16><<<dim3(43, 4, 8), 256, 0, stream>>>(x1, w2, b2, x2);
  conv3x3s2_lrelu<64, 104, 104, 16><<<dim3(11, 8, 8), 256, 0, stream>>>(x2, w3, b3, x3);
  conv3x3s2_lrelu<128, 52, 52, 16><<<dim3(3, 16, 8), 256, 0, stream>>>(x3, w4, b4, x4);
  conv1x1_head<256, 15><<<dim3(3, 17, 8), 256, 0, stream>>>(x4, wh2, bh2, f2, 676);
  conv3x3s2_lrelu<256, 26, 26, 8><<<dim3(1, 64, 8), 256, 0, stream>>>(x4, w5, b5, x5);
  conv1x1_head<512, 5><<<dim3(1, 51, 8), 256, 0, stream>>>(x5, wh1, bh1, f1, 169);
  decode_kernel<<<80, 256, 0, stream>>>(f1, f2, cd, keys);
  rank_select_kernel<<<dim3(10, 8), 256, 0, stream>>>(keys, sel);
  nms_kernel<<<8, 256, 0, stream>>>(cd, sel, (float*)d_out);
}